// Round 2
// baseline (755.671 us; speedup 1.0000x reference)
//
#include <hip/hip_runtime.h>
#include <stdint.h>

#define NN    6000
#define KNNC  10
#define MM    (NN * 2 * (KNNC + 1))   // 132000
#define DD    (2 * NN)                // 12000
#define LCH   3                       // hidden layers (LC-1)
#define BLK   256

// Fused: zero the 576MB f32 output (grid-stride float4 stores, issued first so
// they drain in the background) + compute the MLP for one row per thread,
// vals -> workspace (f32).
__global__ __launch_bounds__(BLK) void fused_mlp_zero(
    const float* __restrict__ CK,    // [MM,3]
    const float* __restrict__ Win,   // [3,64]
    const float* __restrict__ bin,   // [64]
    const float* __restrict__ Whid,  // [3,64,64]
    const float* __restrict__ bhid,  // [3,64]
    const float* __restrict__ Wout,  // [64,4]
    const float* __restrict__ bout,  // [4]
    float* __restrict__ vals,        // [MM,2] (workspace)
    float* __restrict__ out)         // [DD*DD], to be zeroed
{
    __shared__ float sWT[LCH * 4096];   // transposed: sWT[l*4096 + j*64 + k] = Whid[l][k][j]
    __shared__ float sWin[3 * 64];
    __shared__ float sBin[64];
    __shared__ float sBhid[LCH * 64];
    __shared__ float sWoutC[64 * 2];    // collapsed over mi: Wout[k][mj] + Wout[k][mj+2]
    __shared__ float sBoutC[2];

    const int tid = threadIdx.x;

    // ---- 1) issue zero-fill stores first so they drain while we compute ----
    {
        float4 z = make_float4(0.f, 0.f, 0.f, 0.f);
        float4* outv = (float4*)out;
        const long long NV = (long long)DD * DD / 4;   // 36,000,000 float4s
        long long i = (long long)blockIdx.x * BLK + tid;
        const long long stride = (long long)gridDim.x * BLK;
        for (; i < NV; i += stride) outv[i] = z;
    }

    // ---- 2) stage weights in LDS (W_hid transposed for float4 K-reads) ----
    if (tid < 192) {                        // one (l,k) pair per thread
        int l = tid >> 6, k = tid & 63;
        const float* src = Whid + (l * 64 + k) * 64;   // row k of layer l
        float* dst = sWT + l * 4096 + k;               // column k, stride 64 in j
        for (int j = 0; j < 64; j++) dst[j * 64] = src[j];
    }
    if (tid < 192) sWin[tid] = Win[tid];
    if (tid < 64)  sBin[tid] = bin[tid];
    if (tid < 192) sBhid[tid] = bhid[tid];
    if (tid < 64) {
        sWoutC[tid * 2 + 0] = Wout[tid * 4 + 0] + Wout[tid * 4 + 2];
        sWoutC[tid * 2 + 1] = Wout[tid * 4 + 1] + Wout[tid * 4 + 3];
    }
    if (tid < 2) sBoutC[tid] = bout[tid] + bout[tid + 2];
    __syncthreads();

    // ---- 3) MLP, one row per thread, all activations in registers ----
    const int m = blockIdx.x * BLK + tid;
    if (m >= MM) return;

    const float x0 = CK[m * 3 + 0];
    const float x1 = CK[m * 3 + 1];
    const float x2 = CK[m * 3 + 2];

    float h[64];
#pragma unroll
    for (int j = 0; j < 64; j++) {
        float a = sBin[j] + x0 * sWin[j] + x1 * sWin[64 + j] + x2 * sWin[128 + j];
        h[j] = fmaxf(a, 0.0f);
    }

    for (int l = 0; l < LCH; l++) {       // rolled: keeps code size ~1 layer
        const float* WT = sWT + (l << 12);
        const float* bh = sBhid + (l << 6);
        float g[64];
#pragma unroll
        for (int j = 0; j < 64; j++) {
            float acc = bh[j];
            const float4* w4 = (const float4*)(WT + (j << 6));  // broadcast reads
#pragma unroll
            for (int k4 = 0; k4 < 16; k4++) {
                float4 w = w4[k4];
                acc += h[k4 * 4 + 0] * w.x;
                acc += h[k4 * 4 + 1] * w.y;
                acc += h[k4 * 4 + 2] * w.z;
                acc += h[k4 * 4 + 3] * w.w;
            }
            g[j] = fmaxf(acc, 0.0f);
        }
#pragma unroll
        for (int j = 0; j < 64; j++) h[j] = g[j];
    }

    float v0 = sBoutC[0], v1 = sBoutC[1];
#pragma unroll
    for (int k = 0; k < 64; k++) {
        float2 wc = *(const float2*)(sWoutC + k * 2);
        v0 += h[k] * wc.x;
        v1 += h[k] * wc.y;
    }
    vals[m * 2 + 0] = v0;
    vals[m * 2 + 1] = v1;
}

__global__ __launch_bounds__(BLK) void scatter_add(
    const float* __restrict__ vals,   // [MM,2]
    const int* __restrict__ coo,      // [2,MM]
    float* __restrict__ out)          // [DD*DD]
{
    const int t = blockIdx.x * BLK + threadIdx.x;
    if (t >= MM) return;
    const int r2 = coo[t] * 2;        // row index * MODES
    const int c2 = coo[MM + t] * 2;   // col index * MODES
    const float v0 = vals[t * 2 + 0];
    const float v1 = vals[t * 2 + 1];
    // mj=0: element (r2, c2); mj=1: element (r2+1, c2+1) = +DD+1 flat
    const long long f0 = (long long)r2 * DD + c2;
    atomicAdd(out + f0, v0);
    atomicAdd(out + f0 + DD + 1, v1);
}

extern "C" void kernel_launch(void* const* d_in, const int* in_sizes, int n_in,
                              void* d_out, int out_size, void* d_ws, size_t ws_size,
                              hipStream_t stream) {
    const float* CK   = (const float*)d_in[0];
    const float* Win  = (const float*)d_in[1];
    const float* bin  = (const float*)d_in[2];
    const float* Whid = (const float*)d_in[3];
    const float* bhid = (const float*)d_in[4];
    const float* Wout = (const float*)d_in[5];
    const float* bout = (const float*)d_in[6];
    const int* coo    = (const int*)d_in[7];
    float* out        = (float*)d_out;
    float* vals       = (float*)d_ws;

    const int blocks = (MM + BLK - 1) / BLK;   // 516

    fused_mlp_zero<<<blocks, BLK, 0, stream>>>(CK, Win, bin, Whid, bhid, Wout, bout, vals, out);
    scatter_add<<<blocks, BLK, 0, stream>>>(vals, coo, out);
}

// Round 3
// 711.430 us; speedup vs baseline: 1.0622x; 1.0622x over previous
//
#include <hip/hip_runtime.h>
#include <stdint.h>

#define NN    6000
#define KNNC  10
#define MM    (NN * 2 * (KNNC + 1))   // 132000
#define DD    (2 * NN)                // 12000
#define LCH   3                       // hidden layers (LC-1)
#define BLK   256

#define MLP_BLOCKS  ((MM + BLK - 1) / BLK)   // 516
#define FILL_BLOCKS 2048

// Block-specialized fused kernel:
//   blocks [0, MLP_BLOCKS)                : MLP, one row per thread, weights read
//                                           via wave-uniform global loads -> s_load
//                                           (SGPR broadcast, no LDS, no VMEM storm)
//   blocks [MLP_BLOCKS, MLP_BLOCKS+FILL)  : zero-fill the 576MB f32 output with
//                                           grid-stride float4 stores
// The two specializations overlap on different pipes (VALU vs store/HBM).
__global__ __launch_bounds__(BLK) void fused_mlp_zero(
    const float* __restrict__ CK,    // [MM,3]
    const float* __restrict__ Win,   // [3,64]
    const float* __restrict__ bin,   // [64]
    const float* __restrict__ Whid,  // [3,64,64]
    const float* __restrict__ bhid,  // [3,64]
    const float* __restrict__ Wout,  // [64,4]
    const float* __restrict__ bout,  // [4]
    float* __restrict__ vals,        // [MM,2] (workspace)
    float* __restrict__ out)         // [DD*DD], to be zeroed
{
    const int tid = threadIdx.x;

    if (blockIdx.x >= MLP_BLOCKS) {
        // ---- zero-fill specialization ----
        const int fb = blockIdx.x - MLP_BLOCKS;
        float4 z = make_float4(0.f, 0.f, 0.f, 0.f);
        float4* outv = (float4*)out;
        const long long NV = (long long)DD * DD / 4;   // 36,000,000 float4s
        long long i = (long long)fb * BLK + tid;
        const long long stride = (long long)FILL_BLOCKS * BLK;
        for (; i < NV; i += stride) outv[i] = z;
        return;
    }

    // ---- MLP specialization: one row per thread ----
    const int m = blockIdx.x * BLK + tid;
    if (m >= MM) return;

    const float x0 = CK[m * 3 + 0];
    const float x1 = CK[m * 3 + 1];
    const float x2 = CK[m * 3 + 2];

    // Input layer: 3 -> 64. All weight/bias indices are wave-uniform -> SGPR.
    float h[64];
#pragma unroll
    for (int j = 0; j < 64; j++) {
        float a = bin[j];
        a = fmaf(x0, Win[j],       a);
        a = fmaf(x1, Win[64 + j],  a);
        a = fmaf(x2, Win[128 + j], a);
        h[j] = fmaxf(a, 0.0f);
    }

    // Hidden layers: 64 -> 64, g_j = sum_k W[k][j] * h_k  (W row-major [k][j],
    // matching h @ W in the reference). Weight loads wave-uniform -> s_load.
    for (int l = 0; l < LCH; l++) {
        const float* __restrict__ W  = Whid + (l << 12);
        const float* __restrict__ bh = bhid + (l << 6);
        float g[64];
#pragma unroll
        for (int j = 0; j < 64; j++) g[j] = bh[j];
        for (int k = 0; k < 64; k++) {
            const float hk = h[k];
            const float* __restrict__ Wk = W + (k << 6);
#pragma unroll
            for (int j = 0; j < 64; j++) g[j] = fmaf(Wk[j], hk, g[j]);
        }
#pragma unroll
        for (int j = 0; j < 64; j++) h[j] = fmaxf(g[j], 0.0f);
    }

    // Output layer collapsed over mi: vals[:,mj] = C[:,mj] + C[:,mj+2]
    float v0 = bout[0] + bout[2];
    float v1 = bout[1] + bout[3];
#pragma unroll
    for (int k = 0; k < 64; k++) {
        v0 = fmaf(h[k], Wout[k * 4 + 0] + Wout[k * 4 + 2], v0);
        v1 = fmaf(h[k], Wout[k * 4 + 1] + Wout[k * 4 + 3], v1);
    }
    vals[m * 2 + 0] = v0;
    vals[m * 2 + 1] = v1;
}

__global__ __launch_bounds__(BLK) void scatter_add(
    const float* __restrict__ vals,   // [MM,2]
    const int* __restrict__ coo,      // [2,MM]
    float* __restrict__ out)          // [DD*DD]
{
    const int t = blockIdx.x * BLK + threadIdx.x;
    if (t >= MM) return;
    const int r2 = coo[t] * 2;        // row index * MODES
    const int c2 = coo[MM + t] * 2;   // col index * MODES
    const float v0 = vals[t * 2 + 0];
    const float v1 = vals[t * 2 + 1];
    // mj=0: element (r2, c2); mj=1: element (r2+1, c2+1) = +DD+1 flat
    const long long f0 = (long long)r2 * DD + c2;
    atomicAdd(out + f0, v0);
    atomicAdd(out + f0 + DD + 1, v1);
}

extern "C" void kernel_launch(void* const* d_in, const int* in_sizes, int n_in,
                              void* d_out, int out_size, void* d_ws, size_t ws_size,
                              hipStream_t stream) {
    const float* CK   = (const float*)d_in[0];
    const float* Win  = (const float*)d_in[1];
    const float* bin  = (const float*)d_in[2];
    const float* Whid = (const float*)d_in[3];
    const float* bhid = (const float*)d_in[4];
    const float* Wout = (const float*)d_in[5];
    const float* bout = (const float*)d_in[6];
    const int* coo    = (const int*)d_in[7];
    float* out        = (float*)d_out;
    float* vals       = (float*)d_ws;

    fused_mlp_zero<<<MLP_BLOCKS + FILL_BLOCKS, BLK, 0, stream>>>(
        CK, Win, bin, Whid, bhid, Wout, bout, vals, out);
    scatter_add<<<MLP_BLOCKS, BLK, 0, stream>>>(vals, coo, out);
}